// Round 3
// baseline (752.446 us; speedup 1.0000x reference)
//
#include <hip/hip_runtime.h>

// Phase 1: per-anchor forward scan for first same-label (pos) and first
// diff-label (neg) index at j > i. Labels (int32 on device, values < 1000)
// fit in 64 KiB LDS; each block stages the whole array once and scans LDS.
__global__ void mine_kernel(const int* __restrict__ labels,
                            int* __restrict__ pos_idx,
                            int* __restrict__ neg_idx,
                            float* __restrict__ valid_out,
                            int N) {
    extern __shared__ int slab[];
    for (int j = threadIdx.x; j < N; j += blockDim.x)
        slab[j] = labels[j];
    __syncthreads();

    int i = blockIdx.x * blockDim.x + threadIdx.x;
    if (i >= N) return;

    int my = slab[i];
    int p = -1, ng = -1;
    for (int j = i + 1; j < N; ++j) {
        int l = slab[j];
        if (p < 0 && l == my) p = j;
        if (ng < 0 && l != my) ng = j;
        if (p >= 0 && ng >= 0) break;
    }
    bool v = (p >= 0) && (ng >= 0);
    pos_idx[i] = (p >= 0) ? p : 0;   // matches argmax(all-False)=0; zeroed anyway
    neg_idx[i] = (ng >= 0) ? ng : 0;
    valid_out[i] = v ? 1.0f : 0.0f;
}

// Phase 2: gather + scale-by-valid, float4-vectorized.
// Output layout: out[t*N*D + i*D + d], t in {anchor, pos, neg}.
__global__ void gather_kernel(const float4* __restrict__ emb,
                              const int* __restrict__ pos_idx,
                              const int* __restrict__ neg_idx,
                              const float* __restrict__ valid,
                              float4* __restrict__ out,
                              int N, int D4, int total) {
    int idx = blockIdx.x * blockDim.x + threadIdx.x;
    if (idx >= total) return;

    int d4   = idx % D4;
    int rest = idx / D4;
    int i    = rest % N;
    int t    = rest / N;

    int src = (t == 0) ? i : ((t == 1) ? pos_idx[i] : neg_idx[i]);
    float v = valid[i];

    float4 e = emb[(size_t)src * D4 + d4];
    out[idx] = make_float4(e.x * v, e.y * v, e.z * v, e.w * v);
}

extern "C" void kernel_launch(void* const* d_in, const int* in_sizes, int n_in,
                              void* d_out, int out_size, void* d_ws, size_t ws_size,
                              hipStream_t stream) {
    const float* emb    = (const float*)d_in[0];
    const int*   labels = (const int*)d_in[1];   // harness passes integers as int32

    int N  = in_sizes[1];           // 16384
    int D  = in_sizes[0] / N;       // 128
    int D4 = D / 4;                 // 32

    float* out       = (float*)d_out;
    float* valid_out = out + (size_t)3 * N * D;   // tail of d_out: [N] valid mask

    int* pos_idx = (int*)d_ws;
    int* neg_idx = pos_idx + N;

    const int block = 256;
    int nblk1 = (N + block - 1) / block;
    mine_kernel<<<nblk1, block, (size_t)N * sizeof(int), stream>>>(
        labels, pos_idx, neg_idx, valid_out, N);

    int total = 3 * N * D4;
    int nblk2 = (total + block - 1) / block;
    gather_kernel<<<nblk2, block, 0, stream>>>(
        (const float4*)emb, pos_idx, neg_idx, valid_out, (float4*)out, N, D4, total);
}

// Round 4
// 39.835 us; speedup vs baseline: 18.8892x; 18.8892x over previous
//
#include <hip/hip_runtime.h>

// Phase 1: ONE WAVE per anchor. The wave scans 64 labels/iteration with a
// coalesced load + ballot; first set bit gives the first match. Expected
// positive gap ~= C = 1000 -> ~16 iterations; negative found in iteration 1.
// Loop is wave-uniform (ballot), so no per-lane divergence tail.
__global__ void mine_wave_kernel(const int* __restrict__ labels,
                                 int* __restrict__ pos_idx,
                                 int* __restrict__ neg_idx,
                                 float* __restrict__ valid_out,
                                 int N) {
    int gtid = blockIdx.x * blockDim.x + threadIdx.x;
    int i    = gtid >> 6;          // wave index == anchor index
    int lane = threadIdx.x & 63;
    if (i >= N) return;

    int my = labels[i];            // broadcast read
    int p = -1, ng = -1;

    for (int base = i + 1; base < N; base += 64) {
        int  j   = base + lane;
        bool inb = (j < N);
        int  l   = inb ? labels[j] : 0;
        unsigned long long bs = __ballot(inb && (l == my));
        unsigned long long bd = __ballot(inb && (l != my));
        if (p  < 0 && bs) p  = base + (int)__ffsll((unsigned long long)bs) - 1;
        if (ng < 0 && bd) ng = base + (int)__ffsll((unsigned long long)bd) - 1;
        if (p >= 0 && ng >= 0) break;
    }

    if (lane == 0) {
        bool v = (p >= 0) && (ng >= 0);
        pos_idx[i]   = (p  >= 0) ? p  : 0;  // index irrelevant when invalid (zeroed)
        neg_idx[i]   = (ng >= 0) ? ng : 0;
        valid_out[i] = v ? 1.0f : 0.0f;
    }
}

// Phase 2: gather + scale-by-valid, float4-vectorized.
// Output layout: out[t*N*D + i*D + d], t in {anchor, pos, neg}.
__global__ void gather_kernel(const float4* __restrict__ emb,
                              const int* __restrict__ pos_idx,
                              const int* __restrict__ neg_idx,
                              const float* __restrict__ valid,
                              float4* __restrict__ out,
                              int N, int D4, int total) {
    int idx = blockIdx.x * blockDim.x + threadIdx.x;
    if (idx >= total) return;

    int d4   = idx % D4;
    int rest = idx / D4;
    int i    = rest % N;
    int t    = rest / N;

    int src = (t == 0) ? i : ((t == 1) ? pos_idx[i] : neg_idx[i]);
    float v = valid[i];

    float4 e = emb[(size_t)src * D4 + d4];
    out[idx] = make_float4(e.x * v, e.y * v, e.z * v, e.w * v);
}

extern "C" void kernel_launch(void* const* d_in, const int* in_sizes, int n_in,
                              void* d_out, int out_size, void* d_ws, size_t ws_size,
                              hipStream_t stream) {
    const float* emb    = (const float*)d_in[0];
    const int*   labels = (const int*)d_in[1];   // harness passes integers as int32

    int N  = in_sizes[1];           // 16384
    int D  = in_sizes[0] / N;       // 128
    int D4 = D / 4;                 // 32

    float* out       = (float*)d_out;
    float* valid_out = out + (size_t)3 * N * D;   // tail of d_out: [N] valid mask

    int* pos_idx = (int*)d_ws;
    int* neg_idx = pos_idx + N;

    const int block = 256;
    // one wave (64 lanes) per anchor -> N*64 threads
    long long threads1 = (long long)N * 64;
    int nblk1 = (int)((threads1 + block - 1) / block);
    mine_wave_kernel<<<nblk1, block, 0, stream>>>(
        labels, pos_idx, neg_idx, valid_out, N);

    int total = 3 * N * D4;
    int nblk2 = (total + block - 1) / block;
    gather_kernel<<<nblk2, block, 0, stream>>>(
        (const float4*)emb, pos_idx, neg_idx, valid_out, (float4*)out, N, D4, total);
}

// Round 5
// 20.614 us; speedup vs baseline: 36.5011x; 1.9324x over previous
//
#include <hip/hip_runtime.h>

// Fused triplet miner: ONE WAVE per anchor.
//  Phase A (mine): scan labels at 256/iteration (int4 per lane), 2-deep
//    register prefetch to hide L2 latency in the serial ballot chain.
//  Phase B (write): the same wave writes its 3 output rows (anchor/pos/neg,
//    512 B each) scaled by the valid flag. Fusion lets straggler miners
//    overlap with other waves' streaming writes.
__global__ void __launch_bounds__(256) triplet_fused_kernel(
    const int* __restrict__ labels,
    const float4* __restrict__ emb,   // [N][D4]
    float4* __restrict__ out,         // [3][N][D4]
    float* __restrict__ valid_out,    // [N]
    int N, int D4) {

    int lane = threadIdx.x & 63;
    int i = blockIdx.x * (blockDim.x >> 6) + (threadIdx.x >> 6);  // anchor
    if (i >= N) return;

    int my = labels[i];                     // broadcast (same per wave)
    const int4* lab4 = (const int4*)labels;
    int nq = N >> 2;                        // int4 chunks (N % 4 == 0)

    int kbase = (i + 1) >> 2;               // first chunk containing j > i
    int p = -1, ng = -1;

    // 2-deep prefetch (clamped addresses; processing is bounds-masked)
    int4 c0 = lab4[min(kbase + lane,       nq - 1)];
    int4 c1 = lab4[min(kbase + 64 + lane,  nq - 1)];

    while (true) {
        int4 c2 = lab4[min(kbase + 128 + lane, nq - 1)];

        int kq = kbase + lane;              // this lane's chunk index
        unsigned ms = 0, md = 0;
        if (kq < nq) {
            int j0 = kq << 2;
            int l0 = c0.x, l1 = c0.y, l2 = c0.z, l3 = c0.w;
            if (j0 + 0 > i) { if (l0 == my) ms |= 1u; else md |= 1u; }
            if (j0 + 1 > i) { if (l1 == my) ms |= 2u; else md |= 2u; }
            if (j0 + 2 > i) { if (l2 == my) ms |= 4u; else md |= 4u; }
            if (j0 + 3 > i) { if (l3 == my) ms |= 8u; else md |= 8u; }
        }

        unsigned long long bs = __ballot(ms != 0);
        unsigned long long bd = __ballot(md != 0);
        if (p < 0 && bs) {
            int ls = (int)__ffsll(bs) - 1;
            unsigned m = __shfl(ms, ls);
            p = ((kbase + ls) << 2) + (__ffs(m) - 1);
        }
        if (ng < 0 && bd) {
            int ld_ = (int)__ffsll(bd) - 1;
            unsigned m = __shfl(md, ld_);
            ng = ((kbase + ld_) << 2) + (__ffs(m) - 1);
        }

        kbase += 64;
        if ((p >= 0 && ng >= 0) || kbase >= nq) break;
        c0 = c1; c1 = c2;
    }

    float v  = (p >= 0 && ng >= 0) ? 1.0f : 0.0f;
    int   ps = (p  >= 0) ? p  : 0;   // index irrelevant when invalid (row zeroed)
    int   ns = (ng >= 0) ? ng : 0;

    if (lane == 0) valid_out[i] = v;

    // Write 3 rows: lanes 0-31 -> anchor row, lanes 32-63 -> pos row,
    // second pass lanes 0-31 -> neg row. Each half-wave writes 512 B coalesced.
    size_t ND4 = (size_t)N * D4;
    int t   = lane >> 5;                    // 0: anchor, 1: pos
    int src = (t == 0) ? i : ps;
    for (int d4 = lane & 31; d4 < D4; d4 += 32) {
        float4 e = emb[(size_t)src * D4 + d4];
        out[(size_t)t * ND4 + (size_t)i * D4 + d4] =
            make_float4(e.x * v, e.y * v, e.z * v, e.w * v);
        if (lane < 32) {
            float4 e2 = emb[(size_t)ns * D4 + d4];
            out[2 * ND4 + (size_t)i * D4 + d4] =
                make_float4(e2.x * v, e2.y * v, e2.z * v, e2.w * v);
        }
    }
}

extern "C" void kernel_launch(void* const* d_in, const int* in_sizes, int n_in,
                              void* d_out, int out_size, void* d_ws, size_t ws_size,
                              hipStream_t stream) {
    const float* emb    = (const float*)d_in[0];
    const int*   labels = (const int*)d_in[1];   // harness passes integers as int32

    int N  = in_sizes[1];           // 16384
    int D  = in_sizes[0] / N;       // 128
    int D4 = D / 4;                 // 32

    float* out       = (float*)d_out;
    float* valid_out = out + (size_t)3 * N * D;  // tail of d_out: [N] valid mask

    const int block = 256;                        // 4 waves = 4 anchors per block
    int anchors_per_block = block / 64;
    int nblk = (N + anchors_per_block - 1) / anchors_per_block;
    triplet_fused_kernel<<<nblk, block, 0, stream>>>(
        labels, (const float4*)emb, (float4*)out, valid_out, N, D4);
}

// Round 6
// 16.192 us; speedup vs baseline: 46.4707x; 1.2731x over previous
//
#include <hip/hip_runtime.h>

typedef float f32x4 __attribute__((ext_vector_type(4)));

// Fused triplet miner: ONE WAVE per anchor.
//  Phase A (mine): scan labels 512/iteration (2x int4 per lane), 2-deep
//    register prefetch hides L2 latency in the serial ballot chain.
//  Phase B (write): same wave writes its 3 output rows (anchor/pos/neg,
//    512 B each) scaled by valid flag, via NON-TEMPORAL stores so the
//    25 MB write stream doesn't evict the 8 MB emb table from L2.
__global__ void __launch_bounds__(256) triplet_fused_kernel(
    const int* __restrict__ labels,
    const f32x4* __restrict__ emb,    // [N][D4]
    f32x4* __restrict__ out,          // [3][N][D4]
    float* __restrict__ valid_out,    // [N]
    int N, int D4) {

    int lane = threadIdx.x & 63;
    int i = blockIdx.x * (blockDim.x >> 6) + (threadIdx.x >> 6);  // anchor
    if (i >= N) return;

    int my = labels[i];                     // wave-uniform broadcast
    const int4* lab4 = (const int4*)labels;
    int nq = N >> 2;                        // int4 chunks (N % 4 == 0)

    int kbase = (i + 1) >> 2;               // first chunk containing j > i
    int p = -1, ng = -1;

    // 2-deep prefetch of 2 chunk-groups per iteration (clamped addresses).
    int4 a0 = lab4[min(kbase +       lane, nq - 1)];
    int4 b0 = lab4[min(kbase +  64 + lane, nq - 1)];
    int4 a1 = lab4[min(kbase + 128 + lane, nq - 1)];
    int4 b1 = lab4[min(kbase + 192 + lane, nq - 1)];

    while (true) {
        int4 a2 = lab4[min(kbase + 256 + lane, nq - 1)];
        int4 b2 = lab4[min(kbase + 320 + lane, nq - 1)];

        unsigned msA = 0, mdA = 0, msB = 0, mdB = 0;
        int kqA = kbase + lane;
        int kqB = kbase + 64 + lane;
        if (kqA < nq) {
            int j0 = kqA << 2;
            if (j0 + 0 > i) { if (a0.x == my) msA |= 1u; else mdA |= 1u; }
            if (j0 + 1 > i) { if (a0.y == my) msA |= 2u; else mdA |= 2u; }
            if (j0 + 2 > i) { if (a0.z == my) msA |= 4u; else mdA |= 4u; }
            if (j0 + 3 > i) { if (a0.w == my) msA |= 8u; else mdA |= 8u; }
        }
        if (kqB < nq) {
            // j0 = kqB*4 > i always holds here (kqB >= kbase+64 > i/4), no mask needed
            if (b0.x == my) msB |= 1u; else mdB |= 1u;
            if (b0.y == my) msB |= 2u; else mdB |= 2u;
            if (b0.z == my) msB |= 4u; else mdB |= 4u;
            if (b0.w == my) msB |= 8u; else mdB |= 8u;
        }

        unsigned long long bsA = __ballot(msA != 0);
        unsigned long long bdA = __ballot(mdA != 0);
        unsigned long long bsB = __ballot(msB != 0);
        unsigned long long bdB = __ballot(mdB != 0);

        if (p < 0) {
            if (bsA) {
                int ls = (int)__ffsll(bsA) - 1;
                unsigned m = __shfl(msA, ls);
                p = ((kbase + ls) << 2) + (__ffs(m) - 1);
            } else if (bsB) {
                int ls = (int)__ffsll(bsB) - 1;
                unsigned m = __shfl(msB, ls);
                p = ((kbase + 64 + ls) << 2) + (__ffs(m) - 1);
            }
        }
        if (ng < 0) {
            if (bdA) {
                int ls = (int)__ffsll(bdA) - 1;
                unsigned m = __shfl(mdA, ls);
                ng = ((kbase + ls) << 2) + (__ffs(m) - 1);
            } else if (bdB) {
                int ls = (int)__ffsll(bdB) - 1;
                unsigned m = __shfl(mdB, ls);
                ng = ((kbase + 64 + ls) << 2) + (__ffs(m) - 1);
            }
        }

        kbase += 128;
        if ((p >= 0 && ng >= 0) || kbase >= nq) break;
        a0 = a1; b0 = b1; a1 = a2; b1 = b2;
    }

    float v  = (p >= 0 && ng >= 0) ? 1.0f : 0.0f;
    int   ps = (p  >= 0) ? p  : 0;   // index irrelevant when invalid (row zeroed)
    int   ns = (ng >= 0) ? ng : 0;

    if (lane == 0) valid_out[i] = v;

    // Write 3 rows (512 B each). Pass 1: lanes 0-31 -> anchor row,
    // lanes 32-63 -> pos row. Pass 2: lanes 0-31 -> neg row.
    size_t ND4 = (size_t)N * D4;
    int t   = lane >> 5;
    int src = (t == 0) ? i : ps;
    int d4  = lane & 31;                    // D4 == 32: one element per lane

    f32x4 e = emb[(size_t)src * D4 + d4];
    f32x4 r; r.x = e.x * v; r.y = e.y * v; r.z = e.z * v; r.w = e.w * v;
    __builtin_nontemporal_store(r, &out[(size_t)t * ND4 + (size_t)i * D4 + d4]);

    if (lane < 32) {
        f32x4 e2 = emb[(size_t)ns * D4 + d4];
        f32x4 r2; r2.x = e2.x * v; r2.y = e2.y * v; r2.z = e2.z * v; r2.w = e2.w * v;
        __builtin_nontemporal_store(r2, &out[2 * ND4 + (size_t)i * D4 + d4]);
    }
}

extern "C" void kernel_launch(void* const* d_in, const int* in_sizes, int n_in,
                              void* d_out, int out_size, void* d_ws, size_t ws_size,
                              hipStream_t stream) {
    const float* emb    = (const float*)d_in[0];
    const int*   labels = (const int*)d_in[1];   // harness passes integers as int32

    int N  = in_sizes[1];           // 16384
    int D  = in_sizes[0] / N;       // 128
    int D4 = D / 4;                 // 32

    float* out       = (float*)d_out;
    float* valid_out = out + (size_t)3 * N * D;  // tail of d_out: [N] valid mask

    const int block = 256;                        // 4 waves = 4 anchors per block
    int anchors_per_block = block / 64;
    int nblk = (N + anchors_per_block - 1) / anchors_per_block;
    triplet_fused_kernel<<<nblk, block, 0, stream>>>(
        labels, (const f32x4*)emb, (f32x4*)out, valid_out, N, D4);
}